// Round 12
// baseline (567.053 us; speedup 1.0000x reference)
//
#include <hip/hip_runtime.h>
#include <hip/hip_bf16.h>

// ---------------------------------------------------------------------------
// FocusPolicy pipeline, MI355X.
//  K0  convert conv1_w + stem_w -> bf16 (fused)       -> w1b, w2b
//  K1 stem conv 7x7/s2 MFMA bf16 + BN partials        -> stem(bf16), partials
//     (TWO output rows per block, shared 10-row slab; 2-half transpose into
//      separate LDS region; (256,3); XCD-swizzled block order)
//  K2 BN finalize                                     -> stats
//  K3 BN apply + relu + maxpool3/2p1 (8 out/thread)   -> f   (16,64,128,128) fp32
//  K4 grid_sample both rotations, banded-LDS          -> xt1, xt2 (bf16)
//  K5 roialign (11 jobs) -> concat (bf16)             -> h   (16,704,23,23)
//  K6 conv1 3x3 (704->64) MFMA bf16, split-K=3, dbuf  -> c1p
//  K6b reduce split-K + bias + BN1 partials (SHUFFLE, no atomics) -> c1, partial
//  K7 BN finalize (shared kernel)                     -> stats1
//  K8 BN+relu+maxpool2/2;  K9 conv2 (LDS);  K10 fc1;  K11 head
// ---------------------------------------------------------------------------

#define C5 0.9961946980917455f
#define S5 0.08715574274765817f

typedef __attribute__((ext_vector_type(8))) short short8;
typedef __attribute__((ext_vector_type(4))) float f32x4;

__device__ __forceinline__ ushort f2bf_bits(float v) {
    __hip_bfloat16 b = __float2bfloat16(v);
    ushort u;
    __builtin_memcpy(&u, &b, 2);
    return u;
}
__device__ __forceinline__ float bfbits2f(ushort u) {
    __hip_bfloat16 b;
    __builtin_memcpy(&b, &u, 2);
    return __bfloat162float(b);
}

// ============ K0: conv1 + stem weights -> bf16 (stem: kh*24+kw*3+ci+3) =====
__global__ __launch_bounds__(256) void k_cvt(const float* __restrict__ w1,
                                             __hip_bfloat16* __restrict__ w1b,
                                             const float* __restrict__ sw,
                                             __hip_bfloat16* __restrict__ w2b) {
    const int t = blockIdx.x * 256 + threadIdx.x;   // 405504 + 12288 = 417792
    if (t < 405504) {
        w1b[t] = __float2bfloat16(w1[t]);
    } else {
        const int e = t - 405504;
        const int oc = e / 192, k = e - oc * 192;
        const int kh = k / 24, u = k - kh * 24;
        float v = 0.f;
        if (u >= 3 && kh < 7) {
            int tt = u - 3;
            int kw = tt / 3, ci = tt - kw * 3;
            v = sw[oc * 147 + ci * 49 + kh * 7 + kw];
        }
        w2b[e] = __float2bfloat16(v);
    }
}

// =================== K1: stem conv MFMA + BN partials ======================
// grid 2048; XCD swizzle: gi = ((bx&7)<<8)+(bx>>3); n = gi>>7, ohp = gi&127.
// Each block computes output rows oh0=2*ohp and oh0+1 from a shared 10-row
// slab (rows ih = 4*ohp-3 .. 4*ohp+6). Pass r uses slab rows (kh + 2r).
// LDS: slab 10x1560 shorts [0,15600) + tile 32x264 [15600,24048) + sred.
__global__ __launch_bounds__(256, 3) void k_stem(const float* __restrict__ x,
                                                 const ushort* __restrict__ w2b,
                                                 __hip_bfloat16* __restrict__ out,
                                                 float* __restrict__ partial) {
    __shared__ __align__(16) ushort smem[24048];
    __shared__ float sredS[4][64], sredQ[4][64];
    const int bx = blockIdx.x;
    const int gi = ((bx & 7) << 8) + (bx >> 3);   // XCD-local row contiguity
    const int ohp = gi & 127;
    const int n  = gi >> 7;
    const int oh0 = ohp * 2;
    const int tid = threadIdx.x;
    const int w = tid >> 6, lane = tid & 63;
    const int quad = lane >> 4, m = lane & 15;

    // ---- phase A: 3900 float4 slots (10 rows x 390), two batched flights --
    // slot e: row = e/390, col = e%390; fc = 4*col-12; valid col in [3,386]
    const float* xn = x + (size_t)n * 786432;
    const int ihb = oh0 * 2 - 3;
    {
        float4 v[8];
#pragma unroll
        for (int i = 0; i < 8; i++) {
            const int e = tid + 256 * i;
            const int row = e / 390, col = e - row * 390;
            const int ih = ihb + row;
            float4 t = {0.f, 0.f, 0.f, 0.f};
            if (col >= 3 && col <= 386 && (unsigned)ih < 512u)
                t = *(const float4*)(xn + (size_t)ih * 1536 + 4 * col - 12);
            v[i] = t;
        }
#pragma unroll
        for (int i = 0; i < 8; i++) {
            const int e = tid + 256 * i;
            const int row = e / 390, col = e - row * 390;
            uint2 p;
            p.x = (uint)f2bf_bits(v[i].x) | ((uint)f2bf_bits(v[i].y) << 16);
            p.y = (uint)f2bf_bits(v[i].z) | ((uint)f2bf_bits(v[i].w) << 16);
            *(uint2*)((uint*)smem + row * 780 + 2 * col) = p;
        }
    }
    {
        float4 v[8];
#pragma unroll
        for (int i = 0; i < 8; i++) {
            const int e = tid + 2048 + 256 * i;
            const int row = e / 390, col = e - row * 390;
            const int ih = ihb + row;
            float4 t = {0.f, 0.f, 0.f, 0.f};
            if (e < 3900 && col >= 3 && col <= 386 && (unsigned)ih < 512u)
                t = *(const float4*)(xn + (size_t)ih * 1536 + 4 * col - 12);
            v[i] = t;
        }
#pragma unroll
        for (int i = 0; i < 8; i++) {
            const int e = tid + 2048 + 256 * i;
            if (e < 3900) {
                const int row = e / 390, col = e - row * 390;
                uint2 p;
                p.x = (uint)f2bf_bits(v[i].x) | ((uint)f2bf_bits(v[i].y) << 16);
                p.y = (uint)f2bf_bits(v[i].z) | ((uint)f2bf_bits(v[i].w) << 16);
                *(uint2*)((uint*)smem + row * 780 + 2 * col) = p;
            }
        }
    }
    __syncthreads();

    ushort* tile = smem + 15600;

    for (int r = 0; r < 2; r++) {
        // ---- K-loop: B-frags from slab rows (kh + 2r) ----
        f32x4 acc[4][4] = {};
#pragma unroll
        for (int ks = 0; ks < 6; ks++) {
            const int g  = ks * 4 + quad;
            const int kh = g / 3;
            const int gi2 = g - kh * 3;
            const uint* rr = (const uint*)smem + (kh + 2 * r) * 780 + 4 * gi2;
            short8 b[4];
#pragma unroll
            for (int nt = 0; nt < 4; nt++) {
                const uint* q = rr + 3 * (w * 64 + nt * 16 + m);
                uint4 t = (uint4){q[0], q[1], q[2], q[3]};
                __builtin_memcpy(&b[nt], &t, 16);
            }
            const int ko = ks * 32 + quad * 8;
#pragma unroll
            for (int mt = 0; mt < 4; mt++) {
                const short8 a = *(const short8*)(w2b + (size_t)(mt * 16 + m) * 192 + ko);
#pragma unroll
                for (int nt = 0; nt < 4; nt++)
                    acc[mt][nt] = __builtin_amdgcn_mfma_f32_16x16x32_bf16(a, b[nt], acc[mt][nt], 0, 0, 0);
            }
        }

        // ---- BN partial sums (this output row) ----
#pragma unroll
        for (int mt = 0; mt < 4; mt++) {
#pragma unroll
            for (int rr2 = 0; rr2 < 4; rr2++) {
                float s = acc[mt][0][rr2] + acc[mt][1][rr2] + acc[mt][2][rr2] + acc[mt][3][rr2];
                float q = acc[mt][0][rr2] * acc[mt][0][rr2] + acc[mt][1][rr2] * acc[mt][1][rr2]
                        + acc[mt][2][rr2] * acc[mt][2][rr2] + acc[mt][3][rr2] * acc[mt][3][rr2];
#pragma unroll
                for (int off = 1; off < 16; off <<= 1) {
                    s += __shfl_xor(s, off, 64);
                    q += __shfl_xor(q, off, 64);
                }
                if (m == 0) {
                    const int ocl = mt * 16 + quad * 4 + rr2;
                    sredS[w][ocl] = s;
                    sredQ[w][ocl] = q;
                }
            }
        }
        __syncthreads();                     // sred visible; prev tile use done
        if (tid < 128) {
            const int oc = tid >> 1, comp = tid & 1;
            float v = 0.f;
#pragma unroll
            for (int ww = 0; ww < 4; ww++)
                v += comp ? sredQ[ww][oc] : sredS[ww][oc];
            partial[(size_t)(bx * 2 + r) * 128 + tid] = v;
        }

        // ---- 2-half transpose (32 oc x 264-pad pos) + coalesced stores ----
        const int oh = oh0 + r;
#pragma unroll
        for (int half = 0; half < 2; half++) {
#pragma unroll
            for (int mi = 0; mi < 2; mi++) {
                const int mt = 2 * half + mi;
#pragma unroll
                for (int nt = 0; nt < 4; nt++) {
                    const int pos = w * 64 + nt * 16 + m;
#pragma unroll
                    for (int rr2 = 0; rr2 < 4; rr2++) {
                        const int ocl = mi * 16 + quad * 4 + rr2;
                        tile[ocl * 264 + pos] = f2bf_bits(acc[mt][nt][rr2]);
                    }
                }
            }
            __syncthreads();
            {
                const int row = tid >> 3, seg = tid & 7;   // 32 rows x 8 segs
                const uint4* src = (const uint4*)&tile[row * 264 + seg * 32];
                uint4 a0 = src[0], a1 = src[1], a2 = src[2], a3 = src[3];
                uint4* d4 = (uint4*)((ushort*)out
                                     + (size_t)(n * 64 + half * 32 + row) * 65536
                                     + oh * 256 + seg * 32);
                d4[0] = a0; d4[1] = a1; d4[2] = a2; d4[3] = a3;
            }
            __syncthreads();
        }
    }
}

// ============ K2/K7: BN finalize (shared; nblk, inv_n parametric) ==========
__global__ __launch_bounds__(256) void k_bnstats(const float* __restrict__ partial,
                                                 int nblk,
                                                 const float* __restrict__ gamma,
                                                 const float* __restrict__ beta,
                                                 float* __restrict__ stats,
                                                 float inv_n) {
    const int c = blockIdx.x;
    const int tid = threadIdx.x;
    float s = 0.f, ss = 0.f;
    for (int b = tid; b < nblk; b += 256) {
        s  += partial[b * 128 + c * 2 + 0];
        ss += partial[b * 128 + c * 2 + 1];
    }
    __shared__ float sh[8], sh2[8];
#pragma unroll
    for (int off = 32; off; off >>= 1) {
        s += __shfl_xor(s, off, 64);
        ss += __shfl_xor(ss, off, 64);
    }
    if ((tid & 63) == 0) { sh[tid >> 6] = s; sh2[tid >> 6] = ss; }
    __syncthreads();
    if (tid == 0) {
        s = sh[0] + sh[1] + sh[2] + sh[3];
        ss = sh2[0] + sh2[1] + sh2[2] + sh2[3];
        float mn = s * inv_n;
        float var = ss * inv_n - mn * mn;
        float a = gamma[c] * rsqrtf(var + 1e-5f);
        stats[c] = a;
        stats[64 + c] = beta[c] - mn * a;
    }
}

// ===== K3: BN apply + relu + maxpool 3x3/s2/p1 — 8 outputs per thread ======
__global__ __launch_bounds__(256) void k_bnpool(const __hip_bfloat16* __restrict__ sin_,
                                                const float* __restrict__ stats,
                                                float* __restrict__ f) {
    const int idx = blockIdx.x * 256 + threadIdx.x;
    const int pwg = idx & 15;
    const int ph = (idx >> 4) & 127;
    const int c = (idx >> 11) & 63;
    const int n = idx >> 17;
    const int pw0 = pwg * 8;
    const float a = stats[c], b = stats[64 + c];
    const uint* base = (const uint*)((const ushort*)sin_ + (size_t)(n * 64 + c) * 65536);

    float colmax[17];
#pragma unroll
    for (int k = 0; k < 17; k++) colmax[k] = -1e30f;

    const int r0 = ph * 2 - 1;
#pragma unroll
    for (int dr = 0; dr < 3; dr++) {
        const int r = r0 + dr;
        const bool rv = (unsigned)r < 256u;
        uint d[9];
        const uint* rp = base + r * 128 + pw0 - 1;
#pragma unroll
        for (int j = 0; j < 9; j++)
            d[j] = (rv && (pw0 > 0 || j > 0)) ? rp[j] : 0u;
#pragma unroll
        for (int j = 0; j < 9; j++) {
            float vhi = a * bfbits2f((ushort)(d[j] >> 16)) + b;
            colmax[2 * j] = rv ? fmaxf(colmax[2 * j], vhi) : colmax[2 * j];
            if (j > 0) {
                float vlo = a * bfbits2f((ushort)(d[j] & 0xFFFFu)) + b;
                colmax[2 * j - 1] = rv ? fmaxf(colmax[2 * j - 1], vlo) : colmax[2 * j - 1];
            }
        }
    }
    if (pw0 == 0) colmax[0] = -1e30f;

    float o[8];
#pragma unroll
    for (int i = 0; i < 8; i++)
        o[i] = fmaxf(fmaxf(colmax[2 * i], fmaxf(colmax[2 * i + 1], colmax[2 * i + 2])), 0.f);
    float* fp = f + (size_t)(n * 64 + c) * 16384 + ph * 128 + pw0;
    *(float4*)fp       = (float4){o[0], o[1], o[2], o[3]};
    *(float4*)(fp + 4) = (float4){o[4], o[5], o[6], o[7]};
}

// ====== K4: grid_sample, both rotations, banded-LDS, bf16 out ==============
__device__ __forceinline__ float gs_tap(const float* band, int nrows, int ry0,
                                        float yy, float xx, float wt) {
    bool valid = (xx >= 0.f) & (xx < 128.f) & (yy >= 0.f) & (yy < 128.f);
    int xi = (int)fminf(fmaxf(xx, 0.f), 127.f);
    int yi = (int)fminf(fmaxf(yy, 0.f), 127.f);
    int r = min(max(yi - ry0, 0), nrows - 1);
    return valid ? band[r * 128 + xi] * wt : 0.f;
}

__device__ __forceinline__ float gs_band(const float* band, int nrows, int ry0,
                                         float ix, float iy) {
    float x0 = floorf(ix), y0 = floorf(iy);
    float lx = ix - x0, ly = iy - y0;
    float wa = (1.f - lx) * (1.f - ly);
    float wb = (1.f - lx) * ly;
    float wc = lx * (1.f - ly);
    float wd = lx * ly;
    return gs_tap(band, nrows, ry0, y0,       x0,       wa)
         + gs_tap(band, nrows, ry0, y0 + 1.f, x0,       wb)
         + gs_tap(band, nrows, ry0, y0,       x0 + 1.f, wc)
         + gs_tap(band, nrows, ry0, y0 + 1.f, x0 + 1.f, wd);
}

__global__ __launch_bounds__(256, 4) void k_gridsample2(const float* __restrict__ f,
                                                        ushort* __restrict__ xt1,
                                                        ushort* __restrict__ xt2) {
    __shared__ float band[78 * 128];
    const int bx = blockIdx.x;
    const int half = bx & 1;
    const int img_i = bx >> 1;          // n*64+c
    const int h0 = half * 64;
    const float gy0 = (2.f * h0 + 1.f) * (1.f / 128.f) - 1.f;
    const float gy1 = (2.f * (h0 + 63) + 1.f) * (1.f / 128.f) - 1.f;
    const float gxm = 255.f * (1.f / 128.f) - 1.f;
    const float iymin = 64.f * (C5 * gy0 - S5 * gxm) + 63.5f;
    const float iymax = 64.f * (C5 * gy1 + S5 * gxm) + 63.5f;
    const int ry0 = max(0, (int)floorf(iymin) - 1);
    const int ry1 = min(127, (int)floorf(iymax) + 2);
    const int nrows = ry1 - ry0 + 1;                 // <= 78
    const float* img = f + (size_t)img_i * 16384;
    const int tid = threadIdx.x;
    const float4* src4 = (const float4*)(img + ry0 * 128);
    for (int e = tid; e < nrows * 32; e += 256)
        ((float4*)band)[e] = src4[e];
    __syncthreads();

    uint* o1 = (uint*)(xt1 + (size_t)img_i * 16384 + h0 * 128);
    uint* o2 = (uint*)(xt2 + (size_t)img_i * 16384 + h0 * 128);
    for (int s = tid; s < 4096; s += 256) {          // pair of w per slot
        const int e = s * 2;
        const int h = h0 + (e >> 7);
        const int w0 = e & 127;
        const float gy = (2 * h + 1) * (1.f / 128.f) - 1.f;
        float r1lo, r1hi, r2lo, r2hi;
#pragma unroll
        for (int d = 0; d < 2; d++) {
            const float gx = (2 * (w0 + d) + 1) * (1.f / 128.f) - 1.f;
            float g0a = C5 * gx + S5 * gy,  g1a = -S5 * gx + C5 * gy;
            float g0b = C5 * gx - S5 * gy,  g1b =  S5 * gx + C5 * gy;
            float v1 = gs_band(band, nrows, ry0, ((g0a + 1.f) * 128.f - 1.f) * 0.5f,
                                                 ((g1a + 1.f) * 128.f - 1.f) * 0.5f);
            float v2 = gs_band(band, nrows, ry0, ((g0b + 1.f) * 128.f - 1.f) * 0.5f,
                                                 ((g1b + 1.f) * 128.f - 1.f) * 0.5f);
            if (d == 0) { r1lo = v1; r2lo = v2; } else { r1hi = v1; r2hi = v2; }
        }
        o1[s] = (uint)f2bf_bits(r1lo) | ((uint)f2bf_bits(r1hi) << 16);
        o2[s] = (uint)f2bf_bits(r2lo) | ((uint)f2bf_bits(r2hi) << 16);
    }
}

// ========= K5: roialign into concat h (bf16); xt sources are bf16 ==========
__global__ __launch_bounds__(256) void k_roialign(const float* __restrict__ f,
                                                  const ushort* __restrict__ xt1,
                                                  const ushort* __restrict__ xt2,
                                                  const float* __restrict__ box,
                                                  __hip_bfloat16* __restrict__ h) {
    const int bx = blockIdx.x;
    const int cg = bx & 7;
    const int job = (bx >> 3) % 11;
    const int n = bx / 88;
    int j, cbase;
    const float* srcf = nullptr;
    const ushort* srcb = nullptr;
    if (job < 7)      { j = job;     cbase = job * 64;             srcf = f;   }
    else if (job < 9) { j = job - 7; cbase = 448 + (job - 7) * 64; srcb = xt1; }
    else              { j = job - 9; cbase = 576 + (job - 9) * 64; srcb = xt2; }
    const float* bp = box + n * 28 + j * 4;
    const float x1 = bp[0] * 0.25f, y1 = bp[1] * 0.25f;
    const float x2 = bp[2] * 0.25f, y2 = bp[3] * 0.25f;
    const float bw = fmaxf(x2 - x1, 1.f) * (1.f / 23.f);
    const float bh = fmaxf(y2 - y1, 1.f) * (1.f / 23.f);
    const size_t ibase = (size_t)(n * 64 + cg * 8) * 16384;
    __hip_bfloat16* hb = h + (size_t)(n * 704 + cbase + cg * 8) * 529;

    for (int pp = threadIdx.x; pp < 529; pp += 256) {
        const int ph = pp / 23, pw = pp - ph * 23;
        int   off[4][4];
        float wt[4][4];
#pragma unroll
        for (int s = 0; s < 4; s++) {
            const int r1 = s >> 1, r2 = s & 1;
            const float yv = y1 + (ph + r1 * 0.5f + 0.25f) * bh;
            const float xv = x1 + (pw + r2 * 0.5f + 0.25f) * bw;
            const bool ok = !(yv < -1.f || yv > 128.f || xv < -1.f || xv > 128.f);
            float y = fminf(fmaxf(yv, 0.f), 127.f);
            float x = fminf(fmaxf(xv, 0.f), 127.f);
            float y0f = floorf(y), x0f = floorf(x);
            int y0 = (int)y0f, x0 = (int)x0f;
            int y1i = min(y0 + 1, 127), x1i = min(x0 + 1, 127);
            float ly = y - y0f, lx = x - x0f;
            float hy = 1.f - ly, hx = 1.f - lx;
            const float sc = ok ? 1.f : 0.f;
            off[s][0] = y0 * 128 + x0;   wt[s][0] = hy * hx * sc;
            off[s][1] = y0 * 128 + x1i;  wt[s][1] = hy * lx * sc;
            off[s][2] = y1i * 128 + x0;  wt[s][2] = ly * hx * sc;
            off[s][3] = y1i * 128 + x1i; wt[s][3] = ly * lx * sc;
        }
        if (job < 7) {
#pragma unroll
            for (int cl = 0; cl < 8; cl++) {
                const float* img = srcf + ibase + (size_t)cl * 16384;
                float sum = 0.f;
#pragma unroll
                for (int s = 0; s < 4; s++)
                    sum += img[off[s][0]] * wt[s][0] + img[off[s][1]] * wt[s][1]
                         + img[off[s][2]] * wt[s][2] + img[off[s][3]] * wt[s][3];
                hb[(size_t)cl * 529 + pp] = __float2bfloat16(sum * 0.25f);
            }
        } else {
#pragma unroll
            for (int cl = 0; cl < 8; cl++) {
                const ushort* img = srcb + ibase + (size_t)cl * 16384;
                float sum = 0.f;
#pragma unroll
                for (int s = 0; s < 4; s++)
                    sum += bfbits2f(img[off[s][0]]) * wt[s][0]
                         + bfbits2f(img[off[s][1]]) * wt[s][1]
                         + bfbits2f(img[off[s][2]]) * wt[s][2]
                         + bfbits2f(img[off[s][3]]) * wt[s][3];
                hb[(size_t)cl * 529 + pp] = __float2bfloat16(sum * 0.25f);
            }
        }
    }
}

// ========= K6: conv1 MFMA bf16, split-K=3, double-buffered staging =========
__global__ __launch_bounds__(256) void k_conv1m(const ushort* __restrict__ hb,
                                                const ushort* __restrict__ w1b,
                                                float* __restrict__ c1p) {
    __shared__ __align__(16) ushort Bs[2][2][32][40];  // [buf][panel][pos][kk]
    const int bx = blockIdx.x;
    const int pt = bx % 17;
    const int n  = (bx / 17) & 15;
    const int s  = bx / 272;
    const int tid = threadIdx.x;
    const int w = tid >> 6, lane = tid & 63;
    const int quad = lane >> 4, m = lane & 15;
    const int kbase = s * 2112;
    const int posb = pt * 32;
    const size_t hb_n = (size_t)n * 704 * 529;
    f32x4 acc0 = {0.f, 0.f, 0.f, 0.f};
    f32x4 acc1 = {0.f, 0.f, 0.f, 0.f};
    const ushort* wrow = w1b + (size_t)(w * 16 + m) * 6336;

    int ep[8], ek[8], epos[8];
#pragma unroll
    for (int i = 0; i < 8; i++) {
        const int e = tid + 256 * i;
        ep[i] = e >> 10; ek[i] = (e >> 5) & 31; epos[i] = e & 31;
    }
    ushort rbuf[8];
#pragma unroll
    for (int i = 0; i < 8; i++) {          // preload it=0
        const int k = kbase + ep[i] * 32 + ek[i];
        const int ci = k / 9, tap = k - ci * 9;
        const int kh = tap / 3, kw = tap - kh * 3;
        rbuf[i] = hb[hb_n + (size_t)ci * 529 + kh * 23 + kw + posb + epos[i]];
    }
#pragma unroll
    for (int i = 0; i < 8; i++) Bs[0][ep[i]][epos[i]][ek[i]] = rbuf[i];

    for (int it = 0; it < 33; it++) {
        __syncthreads();                    // Bs[it&1] ready
        const int cur = it & 1;
        if (it < 32) {
            const int k0 = kbase + (it + 1) * 64;
#pragma unroll
            for (int i = 0; i < 8; i++) {
                const int k = k0 + ep[i] * 32 + ek[i];
                const int ci = k / 9, tap = k - ci * 9;
                const int kh = tap / 3, kw = tap - kh * 3;
                rbuf[i] = hb[hb_n + (size_t)ci * 529 + kh * 23 + kw + posb + epos[i]];
            }
        }
        const int k0 = kbase + it * 64;
        const short8 a0  = *(const short8*)(wrow + k0 + quad * 8);
        const short8 a1  = *(const short8*)(wrow + k0 + 32 + quad * 8);
        const short8 b00 = *(const short8*)&Bs[cur][0][m][quad * 8];
        const short8 b01 = *(const short8*)&Bs[cur][0][16 + m][quad * 8];
        const short8 b10 = *(const short8*)&Bs[cur][1][m][quad * 8];
        const short8 b11 = *(const short8*)&Bs[cur][1][16 + m][quad * 8];
        acc0 = __builtin_amdgcn_mfma_f32_16x16x32_bf16(a0, b00, acc0, 0, 0, 0);
        acc1 = __builtin_amdgcn_mfma_f32_16x16x32_bf16(a0, b01, acc1, 0, 0, 0);
        acc0 = __builtin_amdgcn_mfma_f32_16x16x32_bf16(a1, b10, acc0, 0, 0, 0);
        acc1 = __builtin_amdgcn_mfma_f32_16x16x32_bf16(a1, b11, acc1, 0, 0, 0);
        if (it < 32) {
#pragma unroll
            for (int i = 0; i < 8; i++) Bs[cur ^ 1][ep[i]][epos[i]][ek[i]] = rbuf[i];
        }
    }
    float* outp = c1p + ((size_t)(s * 16 + n) * 64) * 544;
#pragma unroll
    for (int r = 0; r < 4; r++) {
        const int oc = w * 16 + quad * 4 + r;
        outp[(size_t)oc * 544 + posb + m]      = acc0[r];
        outp[(size_t)oc * 544 + posb + 16 + m] = acc1[r];
    }
}

// == K6b: split-K reduce + bias + BN1 partials via SHUFFLE (no atomics) =====
// Block covers 256 consecutive t -> at most 2 distinct rows key = t/441.
__global__ __launch_bounds__(256) void k_c1red(const float* __restrict__ c1p,
                                               const float* __restrict__ b1,
                                               float* __restrict__ c1,
                                               float* __restrict__ partial) {
    __shared__ float red[4][4];
    const int tid = threadIdx.x;
    const int bx = blockIdx.x;
    const int t = bx * 256 + tid;   // 451584 exact
    const int key = t / 441;        // n*64 + oc
    const int p = t - key * 441;
    const int oc = key & 63;
    const int ph = p / 21, pw = p - ph * 21;
    const int p529 = ph * 23 + pw;
    const size_t base = (size_t)key * 544 + p529;
    const size_t sstr = (size_t)16 * 64 * 544;
    const float v = c1p[base] + c1p[base + sstr] + c1p[base + 2 * sstr] + b1[oc];
    c1[t] = v;

    const int key0 = (bx * 256) / 441;
    const bool is0 = (key == key0);
    float s0 = is0 ? v : 0.f, q0 = is0 ? v * v : 0.f;
    float s1 = is0 ? 0.f : v, q1 = is0 ? 0.f : v * v;
#pragma unroll
    for (int off = 1; off < 64; off <<= 1) {
        s0 += __shfl_xor(s0, off, 64);
        q0 += __shfl_xor(q0, off, 64);
        s1 += __shfl_xor(s1, off, 64);
        q1 += __shfl_xor(q1, off, 64);
    }
    const int w = tid >> 6;
    if ((tid & 63) == 0) {
        red[w][0] = s0; red[w][1] = q0; red[w][2] = s1; red[w][3] = q1;
    }
    __syncthreads();
    if (tid < 128) {
        const int c = tid >> 1, comp = tid & 1;
        const float r0 = red[0][comp] + red[1][comp] + red[2][comp] + red[3][comp];
        const float r1 = red[0][2 + comp] + red[1][2 + comp]
                       + red[2][2 + comp] + red[3][2 + comp];
        const int oc0 = key0 & 63, oc1 = (key0 + 1) & 63;
        float val = (c == oc0) ? r0 : ((c == oc1) ? r1 : 0.f);
        partial[(size_t)bx * 128 + tid] = val;
    }
}

// ================ K8: BN1 apply + relu + maxpool 2x2/s2 ====================
__global__ __launch_bounds__(256) void k_bnpool2(const float* __restrict__ c1,
                                                 const float* __restrict__ stats1,
                                                 float* __restrict__ p1) {
    const int t = blockIdx.x * 256 + threadIdx.x;   // 102400 exact
    const int pw = t % 10;
    const int ph = (t / 10) % 10;
    const int c = (t / 100) % 64;
    const int n = t / 6400;
    const float a = stats1[c], b = stats1[64 + c];
    const float* base = c1 + (size_t)(n * 64 + c) * 441;
    const int r = ph * 2, cc = pw * 2;
    float v0 = a * base[r * 21 + cc] + b;
    float v1 = a * base[r * 21 + cc + 1] + b;
    float v2 = a * base[(r + 1) * 21 + cc] + b;
    float v3 = a * base[(r + 1) * 21 + cc + 1] + b;
    p1[t] = fmaxf(fmaxf(fmaxf(v0, v1), fmaxf(v2, v3)), 0.f);
}

// ========== K9: conv2 3x3 (64->32) + bias + relu, LDS-staged ===============
__global__ __launch_bounds__(256) void k_conv2(const float* __restrict__ p1,
                                               const float* __restrict__ w2,
                                               const float* __restrict__ b2,
                                               float* __restrict__ c2) {
    __shared__ float ip[6400];      // 64 ci x 100
    __shared__ float wl[2304];      // 4 oc x 576
    const int bx = blockIdx.x;
    const int n = bx >> 3, ocq = bx & 7;
    const int tid = threadIdx.x;
    const float4* p14 = (const float4*)(p1 + (size_t)n * 6400);
    float4* ip4 = (float4*)ip;
    for (int e = tid; e < 1600; e += 256) ip4[e] = p14[e];
    for (int e = tid; e < 2304; e += 256) wl[e] = w2[ocq * 2304 + e];
    __syncthreads();

    const int ocl = tid >> 6, pos = tid & 63;
    const int ph = pos >> 3, pw = pos & 7;
    const int oc = ocq * 4 + ocl;
    float s = b2[oc];
    const float* wb = wl + ocl * 576;
    const float* ib = ip + ph * 10 + pw;
    for (int ci = 0; ci < 64; ci++) {
        const float* r = ib + ci * 100;
        const float* ww = wb + ci * 9;
        s += r[0] * ww[0] + r[1] * ww[1] + r[2] * ww[2]
           + r[10] * ww[3] + r[11] * ww[4] + r[12] * ww[5]
           + r[20] * ww[6] + r[21] * ww[7] + r[22] * ww[8];
    }
    c2[(size_t)(n * 32 + oc) * 64 + pos] = fmaxf(s, 0.f);
}

// ======================= K10: fc1 + relu ===================================
__global__ __launch_bounds__(64) void k_fc1(const float* __restrict__ c2,
                                            const float* __restrict__ fw,
                                            const float* __restrict__ fb,
                                            float* __restrict__ fo) {
    const int bx = blockIdx.x;
    const int oc = bx & 127, n = bx >> 7;
    const int lane = threadIdx.x;
    const float* a = c2 + (size_t)n * 2048;
    const float* w = fw + (size_t)oc * 2048;
    float s = 0.f;
    for (int k = lane; k < 2048; k += 64) s += a[k] * w[k];
#pragma unroll
    for (int off = 32; off; off >>= 1) s += __shfl_xor(s, off, 64);
    if (lane == 0) fo[n * 128 + oc] = fmaxf(s + fb[oc], 0.f);
}

// ======================= K11: head + tanh ==================================
__global__ __launch_bounds__(64) void k_head(const float* __restrict__ fo,
                                             const float* __restrict__ hw,
                                             const float* __restrict__ hb,
                                             float* __restrict__ out) {
    const int bx = blockIdx.x;
    const int oc = bx % 12, n = bx / 12;
    const int lane = threadIdx.x;
    float s = 0.f;
    for (int k = lane; k < 128; k += 64) s += fo[n * 128 + k] * hw[oc * 128 + k];
#pragma unroll
    for (int off = 32; off; off >>= 1) s += __shfl_xor(s, off, 64);
    if (lane == 0) out[bx] = tanhf(s + hb[oc]);
}

// ===========================================================================
extern "C" void kernel_launch(void* const* d_in, const int* in_sizes, int n_in,
                              void* d_out, int out_size, void* d_ws, size_t ws_size,
                              hipStream_t stream) {
    const float* x       = (const float*)d_in[0];
    const float* box     = (const float*)d_in[1];
    const float* stem_w  = (const float*)d_in[2];
    const float* stem_g  = (const float*)d_in[3];
    const float* stem_b  = (const float*)d_in[4];
    const float* conv1_w = (const float*)d_in[5];
    const float* conv1_b = (const float*)d_in[6];
    const float* bn1_g   = (const float*)d_in[7];
    const float* bn1_b   = (const float*)d_in[8];
    const float* conv2_w = (const float*)d_in[9];
    const float* conv2_b = (const float*)d_in[10];
    const float* fc1_w   = (const float*)d_in[11];
    const float* fc1_b   = (const float*)d_in[12];
    const float* head_w  = (const float*)d_in[13];
    const float* head_b  = (const float*)d_in[14];
    float* out = (float*)d_out;
    float* w = (float*)d_ws;

    const size_t F_SZ = 16777216;                         // 16*64*128*128
    float* f   = w;                                       // fp32
    __hip_bfloat16* stem = (__hip_bfloat16*)(w + F_SZ);   // bf16, spans 2*F_SZ floats
    ushort* xt1 = (ushort*)(w + F_SZ);                    // bf16, aliases stem (dead after K3)
    ushort* xt2 = xt1 + F_SZ;                             // bf16
    float* base3 = w + 3 * F_SZ;
    __hip_bfloat16* hbuf = (__hip_bfloat16*)base3;        // 5958656 els = 2979328+pad
    float* c1   = base3 + 2979392;                        // 451584
    float* c1p  = c1 + 451584;                            // 3*16*64*544 = 1671168
    float* p1   = c1p + 1671168;                          // 102400
    float* c2   = p1 + 102400;                            // 32768
    float* fo   = c2 + 32768;                             // 2048
    float* partial = fo + 2048;                           // max(4096,1764)*128 used
    float* stats   = partial + 1048576;                   // 128
    float* stats1  = stats + 128;                         // 128
    __hip_bfloat16* w1b = (__hip_bfloat16*)(stats1 + 128); // 405504 els
    __hip_bfloat16* w2b = (__hip_bfloat16*)(stats1 + 128 + 202752); // 12288 els

    k_cvt<<<1632, 256, 0, stream>>>(conv1_w, w1b, stem_w, w2b);
    k_stem<<<2048, 256, 0, stream>>>(x, (const ushort*)w2b, stem, partial);
    k_bnstats<<<64, 256, 0, stream>>>(partial, 4096, stem_g, stem_b, stats,
                                      1.f / 1048576.f);
    k_bnpool<<<8192, 256, 0, stream>>>(stem, stats, f);
    k_gridsample2<<<2048, 256, 0, stream>>>(f, xt1, xt2);
    k_roialign<<<1408, 256, 0, stream>>>(f, xt1, xt2, box, hbuf);
    k_conv1m<<<816, 256, 0, stream>>>((const ushort*)hbuf, (const ushort*)w1b, c1p);
    k_c1red<<<1764, 256, 0, stream>>>(c1p, conv1_b, c1, partial);
    k_bnstats<<<64, 256, 0, stream>>>(partial, 1764, bn1_g, bn1_b, stats1,
                                      1.f / 7056.f);
    k_bnpool2<<<400, 256, 0, stream>>>(c1, stats1, p1);
    k_conv2<<<128, 256, 0, stream>>>(p1, conv2_w, conv2_b, c2);
    k_fc1<<<2048, 64, 0, stream>>>(c2, fc1_w, fc1_b, fo);
    k_head<<<192, 64, 0, stream>>>(fo, head_w, head_b, out);
}

// Round 13
// 529.561 us; speedup vs baseline: 1.0708x; 1.0708x over previous
//
#include <hip/hip_runtime.h>
#include <hip/hip_bf16.h>

// ---------------------------------------------------------------------------
// FocusPolicy pipeline, MI355X.  (Best-known config: R10 pipeline + R11 stem
// single-flight phase A. fp32 xt1/xt2; simple c1red; separate bn1stats.)
//  K0  convert conv1_w + stem_w -> bf16 (fused)       -> w1b, w2b
//  K1 stem conv 7x7/s2 MFMA bf16 + BN partials        -> stem(bf16), partials
//     (1 row/block; single 13-load flight; 25 KB LDS; (256,3) spill-free;
//      XCD-swizzled block order for input-row L2 locality)
//  K2 BN finalize                                     -> stats
//  K3 BN apply + relu + maxpool3/2p1 (8 out/thread)   -> f   (16,64,128,128)
//  K4 grid_sample both rotations, banded-LDS (fp32)   -> xt1, xt2
//  K5 roialign (11 jobs) -> concat (bf16)             -> h   (16,704,23,23)
//  K6 conv1 3x3 (704->64) MFMA bf16, split-K=3, dbuf  -> c1p
//  K6b reduce split-K + bias                          -> c1  (16,64,21,21)
//  K7 BN1 stats;  K8 BN+relu+maxpool2/2;  K9 conv2 (LDS);  K10 fc1;  K11 head
// ---------------------------------------------------------------------------

#define C5 0.9961946980917455f
#define S5 0.08715574274765817f

typedef __attribute__((ext_vector_type(8))) short short8;
typedef __attribute__((ext_vector_type(4))) float f32x4;

__device__ __forceinline__ ushort f2bf_bits(float v) {
    __hip_bfloat16 b = __float2bfloat16(v);
    ushort u;
    __builtin_memcpy(&u, &b, 2);
    return u;
}
__device__ __forceinline__ float bfbits2f(ushort u) {
    __hip_bfloat16 b;
    __builtin_memcpy(&b, &u, 2);
    return __bfloat162float(b);
}

// ============ K0: conv1 + stem weights -> bf16 (stem: kh*24+kw*3+ci+3) =====
__global__ __launch_bounds__(256) void k_cvt(const float* __restrict__ w1,
                                             __hip_bfloat16* __restrict__ w1b,
                                             const float* __restrict__ sw,
                                             __hip_bfloat16* __restrict__ w2b) {
    const int t = blockIdx.x * 256 + threadIdx.x;   // 405504 + 12288 = 417792
    if (t < 405504) {
        w1b[t] = __float2bfloat16(w1[t]);
    } else {
        const int e = t - 405504;
        const int oc = e / 192, k = e - oc * 192;
        const int kh = k / 24, u = k - kh * 24;
        float v = 0.f;
        if (u >= 3 && kh < 7) {
            int tt = u - 3;
            int kw = tt / 3, ci = tt - kw * 3;
            v = sw[oc * 147 + ci * 49 + kh * 7 + kw];
        }
        w2b[e] = __float2bfloat16(v);
    }
}

// =================== K1: stem conv MFMA + BN partials ======================
// grid 4096; XCD swizzle: gi = ((bx&7)<<9)+(bx>>3); n = gi>>8, oh = gi&255.
// block 256 = 4 waves; M=64 oc, N=256 positions, K=192.
// smem (12480 shorts ~ 25 KB) = slab 8x1560 OR half-tile 32x264.
// (256,3): spill-free — do NOT raise min-waves or grow the slab (r9/r12).
__global__ __launch_bounds__(256, 3) void k_stem(const float* __restrict__ x,
                                                 const ushort* __restrict__ w2b,
                                                 __hip_bfloat16* __restrict__ out,
                                                 float* __restrict__ partial) {
    __shared__ __align__(16) ushort smem[12480];
    __shared__ float sredS[4][64], sredQ[4][64];
    const int bx = blockIdx.x;
    const int gi = ((bx & 7) << 9) + (bx >> 3);   // XCD-local oh contiguity
    const int oh = gi & 255;
    const int n  = gi >> 8;
    const int tid = threadIdx.x;
    const int w = tid >> 6, lane = tid & 63;
    const int quad = lane >> 4, m = lane & 15;

    // ---- phase A: 3120 float4 slots, ONE batched flight of 13 ----
    // slot e: row = e/390, col = e%390; fc = 4*col-12; valid col in [3,386]
    const float* xn = x + (size_t)n * 786432;
    {
        float4 v[13];
#pragma unroll
        for (int i = 0; i < 13; i++) {
            const int e = tid + 256 * i;
            const int row = e / 390, col = e - row * 390;
            const int ih = oh * 2 - 3 + row;
            float4 t = {0.f, 0.f, 0.f, 0.f};
            if (e < 3120 && col >= 3 && col <= 386 && (unsigned)ih < 512u)
                t = *(const float4*)(xn + (size_t)ih * 1536 + 4 * col - 12);
            v[i] = t;
        }
#pragma unroll
        for (int i = 0; i < 13; i++) {
            const int e = tid + 256 * i;
            if (e < 3120) {
                const int row = e / 390, col = e - row * 390;
                uint2 p;
                p.x = (uint)f2bf_bits(v[i].x) | ((uint)f2bf_bits(v[i].y) << 16);
                p.y = (uint)f2bf_bits(v[i].z) | ((uint)f2bf_bits(v[i].w) << 16);
                *(uint2*)((uint*)smem + row * 780 + 2 * col) = p;
            }
        }
    }
    __syncthreads();

    // ---- K-loop: B-frags straight from slab (sliding-window im2col) ----
    f32x4 acc[4][4] = {};
#pragma unroll
    for (int ks = 0; ks < 6; ks++) {
        const int g  = ks * 4 + quad;
        const int kh = g / 3;
        const int gi2 = g - kh * 3;
        const uint* rr = (const uint*)smem + kh * 780 + 4 * gi2;
        short8 b[4];
#pragma unroll
        for (int nt = 0; nt < 4; nt++) {
            const uint* q = rr + 3 * (w * 64 + nt * 16 + m);
            uint4 t = (uint4){q[0], q[1], q[2], q[3]};
            __builtin_memcpy(&b[nt], &t, 16);
        }
        const int ko = ks * 32 + quad * 8;
#pragma unroll
        for (int mt = 0; mt < 4; mt++) {
            const short8 a = *(const short8*)(w2b + (size_t)(mt * 16 + m) * 192 + ko);
#pragma unroll
            for (int nt = 0; nt < 4; nt++)
                acc[mt][nt] = __builtin_amdgcn_mfma_f32_16x16x32_bf16(a, b[nt], acc[mt][nt], 0, 0, 0);
        }
    }

    // ---- BN partial sums ----
#pragma unroll
    for (int mt = 0; mt < 4; mt++) {
#pragma unroll
        for (int r = 0; r < 4; r++) {
            float s = acc[mt][0][r] + acc[mt][1][r] + acc[mt][2][r] + acc[mt][3][r];
            float q = acc[mt][0][r] * acc[mt][0][r] + acc[mt][1][r] * acc[mt][1][r]
                    + acc[mt][2][r] * acc[mt][2][r] + acc[mt][3][r] * acc[mt][3][r];
#pragma unroll
            for (int off = 1; off < 16; off <<= 1) {
                s += __shfl_xor(s, off, 64);
                q += __shfl_xor(q, off, 64);
            }
            if (m == 0) {
                const int ocl = mt * 16 + quad * 4 + r;
                sredS[w][ocl] = s;
                sredQ[w][ocl] = q;
            }
        }
    }
    __syncthreads();                     // slab dead; sred visible

    // ---- 2-half transpose (32 oc x 264-pad pos) + coalesced stores ----
#pragma unroll
    for (int half = 0; half < 2; half++) {
#pragma unroll
        for (int mi = 0; mi < 2; mi++) {
            const int mt = 2 * half + mi;
#pragma unroll
            for (int nt = 0; nt < 4; nt++) {
                const int pos = w * 64 + nt * 16 + m;
#pragma unroll
                for (int r = 0; r < 4; r++) {
                    const int ocl = mi * 16 + quad * 4 + r;
                    smem[ocl * 264 + pos] = f2bf_bits(acc[mt][nt][r]);
                }
            }
        }
        __syncthreads();
        {
            const int row = tid >> 3, seg = tid & 7;   // 32 rows x 8 segs x 32 pos
            const uint4* src = (const uint4*)&smem[row * 264 + seg * 32];
            uint4 a0 = src[0], a1 = src[1], a2 = src[2], a3 = src[3];
            uint4* d4 = (uint4*)((ushort*)out
                                 + (size_t)(n * 64 + half * 32 + row) * 65536
                                 + oh * 256 + seg * 32);
            d4[0] = a0; d4[1] = a1; d4[2] = a2; d4[3] = a3;
        }
        __syncthreads();
    }

    if (tid < 128) {
        const int oc = tid >> 1, comp = tid & 1;
        float v = 0.f;
#pragma unroll
        for (int ww = 0; ww < 4; ww++)
            v += comp ? sredQ[ww][oc] : sredS[ww][oc];
        partial[bx * 128 + tid] = v;
    }
}

// ============ K2: BN finalize (shared; nblk, inv_n parametric) =============
__global__ __launch_bounds__(256) void k_bnstats(const float* __restrict__ partial,
                                                 int nblk,
                                                 const float* __restrict__ gamma,
                                                 const float* __restrict__ beta,
                                                 float* __restrict__ stats,
                                                 float inv_n) {
    const int c = blockIdx.x;
    const int tid = threadIdx.x;
    float s = 0.f, ss = 0.f;
    for (int b = tid; b < nblk; b += 256) {
        s  += partial[b * 128 + c * 2 + 0];
        ss += partial[b * 128 + c * 2 + 1];
    }
    __shared__ float sh[8], sh2[8];
#pragma unroll
    for (int off = 32; off; off >>= 1) {
        s += __shfl_xor(s, off, 64);
        ss += __shfl_xor(ss, off, 64);
    }
    if ((tid & 63) == 0) { sh[tid >> 6] = s; sh2[tid >> 6] = ss; }
    __syncthreads();
    if (tid == 0) {
        s = sh[0] + sh[1] + sh[2] + sh[3];
        ss = sh2[0] + sh2[1] + sh2[2] + sh2[3];
        float mn = s * inv_n;
        float var = ss * inv_n - mn * mn;
        float a = gamma[c] * rsqrtf(var + 1e-5f);
        stats[c] = a;
        stats[64 + c] = beta[c] - mn * a;
    }
}

__global__ __launch_bounds__(256) void k_bn1stats(const float* __restrict__ c1,
                                                  const float* __restrict__ gamma,
                                                  const float* __restrict__ beta,
                                                  float* __restrict__ stats1) {
    const int c = blockIdx.x;
    const int tid = threadIdx.x;
    float s = 0.f, ss = 0.f;
    for (int e = tid; e < 7056; e += 256) {
        int n = e / 441, p = e - n * 441;
        float v = c1[(n * 64 + c) * 441 + p];
        s += v; ss += v * v;
    }
    __shared__ float sh[8], sh2[8];
#pragma unroll
    for (int off = 32; off; off >>= 1) {
        s += __shfl_xor(s, off, 64);
        ss += __shfl_xor(ss, off, 64);
    }
    if ((tid & 63) == 0) { sh[tid >> 6] = s; sh2[tid >> 6] = ss; }
    __syncthreads();
    if (tid == 0) {
        s = sh[0] + sh[1] + sh[2] + sh[3];
        ss = sh2[0] + sh2[1] + sh2[2] + sh2[3];
        const float inv_n = 1.f / 7056.f;
        float mn = s * inv_n;
        float var = ss * inv_n - mn * mn;
        float a = gamma[c] * rsqrtf(var + 1e-5f);
        stats1[c] = a;
        stats1[64 + c] = beta[c] - mn * a;
    }
}

// ===== K3: BN apply + relu + maxpool 3x3/s2/p1 — 8 outputs per thread ======
__global__ __launch_bounds__(256) void k_bnpool(const __hip_bfloat16* __restrict__ sin_,
                                                const float* __restrict__ stats,
                                                float* __restrict__ f) {
    const int idx = blockIdx.x * 256 + threadIdx.x;
    const int pwg = idx & 15;
    const int ph = (idx >> 4) & 127;
    const int c = (idx >> 11) & 63;
    const int n = idx >> 17;
    const int pw0 = pwg * 8;
    const float a = stats[c], b = stats[64 + c];
    const uint* base = (const uint*)((const ushort*)sin_ + (size_t)(n * 64 + c) * 65536);

    float colmax[17];
#pragma unroll
    for (int k = 0; k < 17; k++) colmax[k] = -1e30f;

    const int r0 = ph * 2 - 1;
#pragma unroll
    for (int dr = 0; dr < 3; dr++) {
        const int r = r0 + dr;
        const bool rv = (unsigned)r < 256u;
        uint d[9];
        const uint* rp = base + r * 128 + pw0 - 1;
#pragma unroll
        for (int j = 0; j < 9; j++)
            d[j] = (rv && (pw0 > 0 || j > 0)) ? rp[j] : 0u;
#pragma unroll
        for (int j = 0; j < 9; j++) {
            float vhi = a * bfbits2f((ushort)(d[j] >> 16)) + b;
            colmax[2 * j] = rv ? fmaxf(colmax[2 * j], vhi) : colmax[2 * j];
            if (j > 0) {
                float vlo = a * bfbits2f((ushort)(d[j] & 0xFFFFu)) + b;
                colmax[2 * j - 1] = rv ? fmaxf(colmax[2 * j - 1], vlo) : colmax[2 * j - 1];
            }
        }
    }
    if (pw0 == 0) colmax[0] = -1e30f;

    float o[8];
#pragma unroll
    for (int i = 0; i < 8; i++)
        o[i] = fmaxf(fmaxf(colmax[2 * i], fmaxf(colmax[2 * i + 1], colmax[2 * i + 2])), 0.f);
    float* fp = f + (size_t)(n * 64 + c) * 16384 + ph * 128 + pw0;
    *(float4*)fp       = (float4){o[0], o[1], o[2], o[3]};
    *(float4*)(fp + 4) = (float4){o[4], o[5], o[6], o[7]};
}

// ====== K4: grid_sample, both rotations, banded-LDS (fp32, bit-identical) ==
__device__ __forceinline__ float gs_tap(const float* band, int nrows, int ry0,
                                        float yy, float xx, float wt) {
    bool valid = (xx >= 0.f) & (xx < 128.f) & (yy >= 0.f) & (yy < 128.f);
    int xi = (int)fminf(fmaxf(xx, 0.f), 127.f);
    int yi = (int)fminf(fmaxf(yy, 0.f), 127.f);
    int r = min(max(yi - ry0, 0), nrows - 1);
    return valid ? band[r * 128 + xi] * wt : 0.f;
}

__device__ __forceinline__ float gs_band(const float* band, int nrows, int ry0,
                                         float ix, float iy) {
    float x0 = floorf(ix), y0 = floorf(iy);
    float lx = ix - x0, ly = iy - y0;
    float wa = (1.f - lx) * (1.f - ly);
    float wb = (1.f - lx) * ly;
    float wc = lx * (1.f - ly);
    float wd = lx * ly;
    return gs_tap(band, nrows, ry0, y0,       x0,       wa)
         + gs_tap(band, nrows, ry0, y0 + 1.f, x0,       wb)
         + gs_tap(band, nrows, ry0, y0,       x0 + 1.f, wc)
         + gs_tap(band, nrows, ry0, y0 + 1.f, x0 + 1.f, wd);
}

__global__ __launch_bounds__(256, 4) void k_gridsample2(const float* __restrict__ f,
                                                        float* __restrict__ xt1,
                                                        float* __restrict__ xt2) {
    __shared__ float band[78 * 128];
    const int bx = blockIdx.x;
    const int half = bx & 1;
    const int img_i = bx >> 1;          // n*64+c
    const int h0 = half * 64;
    const float gy0 = (2.f * h0 + 1.f) * (1.f / 128.f) - 1.f;
    const float gy1 = (2.f * (h0 + 63) + 1.f) * (1.f / 128.f) - 1.f;
    const float gxm = 255.f * (1.f / 128.f) - 1.f;
    const float iymin = 64.f * (C5 * gy0 - S5 * gxm) + 63.5f;
    const float iymax = 64.f * (C5 * gy1 + S5 * gxm) + 63.5f;
    const int ry0 = max(0, (int)floorf(iymin) - 1);
    const int ry1 = min(127, (int)floorf(iymax) + 2);
    const int nrows = ry1 - ry0 + 1;                 // <= 78
    const float* img = f + (size_t)img_i * 16384;
    const int tid = threadIdx.x;
    const float4* src4 = (const float4*)(img + ry0 * 128);
    for (int e = tid; e < nrows * 32; e += 256)
        ((float4*)band)[e] = src4[e];
    __syncthreads();

    float* o1 = xt1 + (size_t)img_i * 16384 + h0 * 128;
    float* o2 = xt2 + (size_t)img_i * 16384 + h0 * 128;
    for (int e = tid; e < 8192; e += 256) {
        const int h = h0 + (e >> 7);
        const int w = e & 127;
        float gx = (2 * w + 1) * (1.f / 128.f) - 1.f;
        float gy = (2 * h + 1) * (1.f / 128.f) - 1.f;
        float g0a = C5 * gx + S5 * gy,  g1a = -S5 * gx + C5 * gy;
        float g0b = C5 * gx - S5 * gy,  g1b =  S5 * gx + C5 * gy;
        o1[e] = gs_band(band, nrows, ry0, ((g0a + 1.f) * 128.f - 1.f) * 0.5f,
                                          ((g1a + 1.f) * 128.f - 1.f) * 0.5f);
        o2[e] = gs_band(band, nrows, ry0, ((g0b + 1.f) * 128.f - 1.f) * 0.5f,
                                          ((g1b + 1.f) * 128.f - 1.f) * 0.5f);
    }
}

// ========= K5: roialign into concat h (bf16), coords once per pp ==========
__global__ __launch_bounds__(256) void k_roialign(const float* __restrict__ f,
                                                  const float* __restrict__ xt1,
                                                  const float* __restrict__ xt2,
                                                  const float* __restrict__ box,
                                                  __hip_bfloat16* __restrict__ h) {
    const int bx = blockIdx.x;
    const int cg = bx & 7;
    const int job = (bx >> 3) % 11;
    const int n = bx / 88;
    int j, cbase;
    const float* src;
    if (job < 7)      { j = job;     cbase = job * 64;             src = f;   }
    else if (job < 9) { j = job - 7; cbase = 448 + (job - 7) * 64; src = xt1; }
    else              { j = job - 9; cbase = 576 + (job - 9) * 64; src = xt2; }
    const float* bp = box + n * 28 + j * 4;
    const float x1 = bp[0] * 0.25f, y1 = bp[1] * 0.25f;
    const float x2 = bp[2] * 0.25f, y2 = bp[3] * 0.25f;
    const float bw = fmaxf(x2 - x1, 1.f) * (1.f / 23.f);
    const float bh = fmaxf(y2 - y1, 1.f) * (1.f / 23.f);
    const float* imgb = src + (size_t)(n * 64 + cg * 8) * 16384;
    __hip_bfloat16* hb = h + (size_t)(n * 704 + cbase + cg * 8) * 529;

    for (int pp = threadIdx.x; pp < 529; pp += 256) {
        const int ph = pp / 23, pw = pp - ph * 23;
        int   off[4][4];
        float wt[4][4];
#pragma unroll
        for (int s = 0; s < 4; s++) {
            const int r1 = s >> 1, r2 = s & 1;
            const float yv = y1 + (ph + r1 * 0.5f + 0.25f) * bh;
            const float xv = x1 + (pw + r2 * 0.5f + 0.25f) * bw;
            const bool ok = !(yv < -1.f || yv > 128.f || xv < -1.f || xv > 128.f);
            float y = fminf(fmaxf(yv, 0.f), 127.f);
            float x = fminf(fmaxf(xv, 0.f), 127.f);
            float y0f = floorf(y), x0f = floorf(x);
            int y0 = (int)y0f, x0 = (int)x0f;
            int y1i = min(y0 + 1, 127), x1i = min(x0 + 1, 127);
            float ly = y - y0f, lx = x - x0f;
            float hy = 1.f - ly, hx = 1.f - lx;
            const float sc = ok ? 1.f : 0.f;
            off[s][0] = y0 * 128 + x0;   wt[s][0] = hy * hx * sc;
            off[s][1] = y0 * 128 + x1i;  wt[s][1] = hy * lx * sc;
            off[s][2] = y1i * 128 + x0;  wt[s][2] = ly * hx * sc;
            off[s][3] = y1i * 128 + x1i; wt[s][3] = ly * lx * sc;
        }
#pragma unroll
        for (int cl = 0; cl < 8; cl++) {
            const float* img = imgb + (size_t)cl * 16384;
            float sum = 0.f;
#pragma unroll
            for (int s = 0; s < 4; s++)
                sum += img[off[s][0]] * wt[s][0] + img[off[s][1]] * wt[s][1]
                     + img[off[s][2]] * wt[s][2] + img[off[s][3]] * wt[s][3];
            hb[(size_t)cl * 529 + pp] = __float2bfloat16(sum * 0.25f);
        }
    }
}

// ========= K6: conv1 MFMA bf16, split-K=3, double-buffered staging =========
__global__ __launch_bounds__(256) void k_conv1m(const ushort* __restrict__ hb,
                                                const ushort* __restrict__ w1b,
                                                float* __restrict__ c1p) {
    __shared__ __align__(16) ushort Bs[2][2][32][40];  // [buf][panel][pos][kk]
    const int bx = blockIdx.x;
    const int pt = bx % 17;
    const int n  = (bx / 17) & 15;
    const int s  = bx / 272;
    const int tid = threadIdx.x;
    const int w = tid >> 6, lane = tid & 63;
    const int quad = lane >> 4, m = lane & 15;
    const int kbase = s * 2112;
    const int posb = pt * 32;
    const size_t hb_n = (size_t)n * 704 * 529;
    f32x4 acc0 = {0.f, 0.f, 0.f, 0.f};
    f32x4 acc1 = {0.f, 0.f, 0.f, 0.f};
    const ushort* wrow = w1b + (size_t)(w * 16 + m) * 6336;

    int ep[8], ek[8], epos[8];
#pragma unroll
    for (int i = 0; i < 8; i++) {
        const int e = tid + 256 * i;
        ep[i] = e >> 10; ek[i] = (e >> 5) & 31; epos[i] = e & 31;
    }
    ushort rbuf[8];
#pragma unroll
    for (int i = 0; i < 8; i++) {          // preload it=0
        const int k = kbase + ep[i] * 32 + ek[i];
        const int ci = k / 9, tap = k - ci * 9;
        const int kh = tap / 3, kw = tap - kh * 3;
        rbuf[i] = hb[hb_n + (size_t)ci * 529 + kh * 23 + kw + posb + epos[i]];
    }
#pragma unroll
    for (int i = 0; i < 8; i++) Bs[0][ep[i]][epos[i]][ek[i]] = rbuf[i];

    for (int it = 0; it < 33; it++) {
        __syncthreads();                    // Bs[it&1] ready
        const int cur = it & 1;
        if (it < 32) {
            const int k0 = kbase + (it + 1) * 64;
#pragma unroll
            for (int i = 0; i < 8; i++) {
                const int k = k0 + ep[i] * 32 + ek[i];
                const int ci = k / 9, tap = k - ci * 9;
                const int kh = tap / 3, kw = tap - kh * 3;
                rbuf[i] = hb[hb_n + (size_t)ci * 529 + kh * 23 + kw + posb + epos[i]];
            }
        }
        const int k0 = kbase + it * 64;
        const short8 a0  = *(const short8*)(wrow + k0 + quad * 8);
        const short8 a1  = *(const short8*)(wrow + k0 + 32 + quad * 8);
        const short8 b00 = *(const short8*)&Bs[cur][0][m][quad * 8];
        const short8 b01 = *(const short8*)&Bs[cur][0][16 + m][quad * 8];
        const short8 b10 = *(const short8*)&Bs[cur][1][m][quad * 8];
        const short8 b11 = *(const short8*)&Bs[cur][1][16 + m][quad * 8];
        acc0 = __builtin_amdgcn_mfma_f32_16x16x32_bf16(a0, b00, acc0, 0, 0, 0);
        acc1 = __builtin_amdgcn_mfma_f32_16x16x32_bf16(a0, b01, acc1, 0, 0, 0);
        acc0 = __builtin_amdgcn_mfma_f32_16x16x32_bf16(a1, b10, acc0, 0, 0, 0);
        acc1 = __builtin_amdgcn_mfma_f32_16x16x32_bf16(a1, b11, acc1, 0, 0, 0);
        if (it < 32) {
#pragma unroll
            for (int i = 0; i < 8; i++) Bs[cur ^ 1][ep[i]][epos[i]][ek[i]] = rbuf[i];
        }
    }
    float* outp = c1p + ((size_t)(s * 16 + n) * 64) * 544;
#pragma unroll
    for (int r = 0; r < 4; r++) {
        const int oc = w * 16 + quad * 4 + r;
        outp[(size_t)oc * 544 + posb + m]      = acc0[r];
        outp[(size_t)oc * 544 + posb + 16 + m] = acc1[r];
    }
}

// =================== K6b: split-K reduce + bias ============================
__global__ __launch_bounds__(256) void k_c1red(const float* __restrict__ c1p,
                                               const float* __restrict__ b1,
                                               float* __restrict__ c1) {
    const int t = blockIdx.x * 256 + threadIdx.x;   // 451584 exact
    const int p = t % 441;
    const int oc = (t / 441) % 64;
    const int n = t / 28224;
    const int ph = p / 21, pw = p - ph * 21;
    const int p529 = ph * 23 + pw;
    const size_t base = ((size_t)n * 64 + oc) * 544 + p529;
    const size_t sstr = (size_t)16 * 64 * 544;
    c1[t] = c1p[base] + c1p[base + sstr] + c1p[base + 2 * sstr] + b1[oc];
}

// ================ K8: BN1 apply + relu + maxpool 2x2/s2 ====================
__global__ __launch_bounds__(256) void k_bnpool2(const float* __restrict__ c1,
                                                 const float* __restrict__ stats1,
                                                 float* __restrict__ p1) {
    const int t = blockIdx.x * 256 + threadIdx.x;   // 102400 exact
    const int pw = t % 10;
    const int ph = (t / 10) % 10;
    const int c = (t / 100) % 64;
    const int n = t / 6400;
    const float a = stats1[c], b = stats1[64 + c];
    const float* base = c1 + (size_t)(n * 64 + c) * 441;
    const int r = ph * 2, cc = pw * 2;
    float v0 = a * base[r * 21 + cc] + b;
    float v1 = a * base[r * 21 + cc + 1] + b;
    float v2 = a * base[(r + 1) * 21 + cc] + b;
    float v3 = a * base[(r + 1) * 21 + cc + 1] + b;
    p1[t] = fmaxf(fmaxf(fmaxf(v0, v1), fmaxf(v2, v3)), 0.f);
}

// ========== K9: conv2 3x3 (64->32) + bias + relu, LDS-staged ===============
__global__ __launch_bounds__(256) void k_conv2(const float* __restrict__ p1,
                                               const float* __restrict__ w2,
                                               const float* __restrict__ b2,
                                               float* __restrict__ c2) {
    __shared__ float ip[6400];      // 64 ci x 100
    __shared__ float wl[2304];      // 4 oc x 576
    const int bx = blockIdx.x;
    const int n = bx >> 3, ocq = bx & 7;
    const int tid = threadIdx.x;
    const float4* p14 = (const float4*)(p1 + (size_t)n * 6400);
    float4* ip4 = (float4*)ip;
    for (int e = tid; e < 1600; e += 256) ip4[e] = p14[e];
    for (int e = tid; e < 2304; e += 256) wl[e] = w2[ocq * 2304 + e];
    __syncthreads();

    const int ocl = tid >> 6, pos = tid & 63;
    const int ph = pos >> 3, pw = pos & 7;
    const int oc = ocq * 4 + ocl;
    float s = b2[oc];
    const float* wb = wl + ocl * 576;
    const float* ib = ip + ph * 10 + pw;
    for (int ci = 0; ci < 64; ci++) {
        const float* r = ib + ci * 100;
        const float* ww = wb + ci * 9;
        s += r[0] * ww[0] + r[1] * ww[1] + r[2] * ww[2]
           + r[10] * ww[3] + r[11] * ww[4] + r[12] * ww[5]
           + r[20] * ww[6] + r[21] * ww[7] + r[22] * ww[8];
    }
    c2[(size_t)(n * 32 + oc) * 64 + pos] = fmaxf(s, 0.f);
}

// ======================= K10: fc1 + relu ===================================
__global__ __launch_bounds__(64) void k_fc1(const float* __restrict__ c2,
                                            const float* __restrict__ fw,
                                            const float* __restrict__ fb,
                                            float* __restrict__ fo) {
    const int bx = blockIdx.x;
    const int oc = bx & 127, n = bx >> 7;
    const int lane = threadIdx.x;
    const float* a = c2 + (size_t)n * 2048;
    const float* w = fw + (size_t)oc * 2048;
    float s = 0.f;
    for (int k = lane; k < 2048; k += 64) s += a[k] * w[k];
#pragma unroll
    for (int off = 32; off; off >>= 1) s += __shfl_xor(s, off, 64);
    if (lane == 0) fo[n * 128 + oc] = fmaxf(s + fb[oc], 0.f);
}

// ======================= K11: head + tanh ==================================
__global__ __launch_bounds__(64) void k_head(const float* __restrict__ fo,
                                             const float* __restrict__ hw,
                                             const float* __restrict__ hb,
                                             float* __restrict__ out) {
    const int bx = blockIdx.x;
    const int oc = bx % 12, n = bx / 12;
    const int lane = threadIdx.x;
    float s = 0.f;
    for (int k = lane; k < 128; k += 64) s += fo[n * 128 + k] * hw[oc * 128 + k];
#pragma unroll
    for (int off = 32; off; off >>= 1) s += __shfl_xor(s, off, 64);
    if (lane == 0) out[bx] = tanhf(s + hb[oc]);
}

// ===========================================================================
extern "C" void kernel_launch(void* const* d_in, const int* in_sizes, int n_in,
                              void* d_out, int out_size, void* d_ws, size_t ws_size,
                              hipStream_t stream) {
    const float* x       = (const float*)d_in[0];
    const float* box     = (const float*)d_in[1];
    const float* stem_w  = (const float*)d_in[2];
    const float* stem_g  = (const float*)d_in[3];
    const float* stem_b  = (const float*)d_in[4];
    const float* conv1_w = (const float*)d_in[5];
    const float* conv1_b = (const float*)d_in[6];
    const float* bn1_g   = (const float*)d_in[7];
    const float* bn1_b   = (const float*)d_in[8];
    const float* conv2_w = (const float*)d_in[9];
    const float* conv2_b = (const float*)d_in[10];
    const float* fc1_w   = (const float*)d_in[11];
    const float* fc1_b   = (const float*)d_in[12];
    const float* head_w  = (const float*)d_in[13];
    const float* head_b  = (const float*)d_in[14];
    float* out = (float*)d_out;
    float* w = (float*)d_ws;

    const size_t F_SZ = 16777216;                         // 16*64*128*128
    float* f   = w;                                       // fp32
    __hip_bfloat16* stem = (__hip_bfloat16*)(w + F_SZ);   // bf16, spans 2*F_SZ floats
    float* xt1 = w + F_SZ;                                // aliases stem (dead after K3)
    float* xt2 = w + 2 * F_SZ;
    float* base3 = w + 3 * F_SZ;
    __hip_bfloat16* hbuf = (__hip_bfloat16*)base3;        // 5958656 els = 2979328+pad
    float* c1   = base3 + 2979392;                        // 451584
    float* c1p  = c1 + 451584;                            // 3*16*64*544 = 1671168
    float* p1   = c1p + 1671168;                          // 102400
    float* c2   = p1 + 102400;                            // 32768
    float* fo   = c2 + 32768;                             // 2048
    float* partial = fo + 2048;                           // 4096*128 used
    float* stats   = partial + 1048576;                   // 128
    float* stats1  = stats + 128;                         // 128
    __hip_bfloat16* w1b = (__hip_bfloat16*)(stats1 + 128); // 405504 els
    __hip_bfloat16* w2b = (__hip_bfloat16*)(stats1 + 128 + 202752); // 12288 els

    k_cvt<<<1632, 256, 0, stream>>>(conv1_w, w1b, stem_w, w2b);
    k_stem<<<4096, 256, 0, stream>>>(x, (const ushort*)w2b, stem, partial);
    k_bnstats<<<64, 256, 0, stream>>>(partial, 4096, stem_g, stem_b, stats,
                                      1.f / 1048576.f);
    k_bnpool<<<8192, 256, 0, stream>>>(stem, stats, f);
    k_gridsample2<<<2048, 256, 0, stream>>>(f, xt1, xt2);
    k_roialign<<<1408, 256, 0, stream>>>(f, xt1, xt2, box, hbuf);
    k_conv1m<<<816, 256, 0, stream>>>((const ushort*)hbuf, (const ushort*)w1b, c1p);
    k_c1red<<<1764, 256, 0, stream>>>(c1p, conv1_b, c1);
    k_bn1stats<<<64, 256, 0, stream>>>(c1, bn1_g, bn1_b, stats1);
    k_bnpool2<<<400, 256, 0, stream>>>(c1, stats1, p1);
    k_conv2<<<128, 256, 0, stream>>>(p1, conv2_w, conv2_b, c2);
    k_fc1<<<2048, 64, 0, stream>>>(c2, fc1_w, fc1_b, fo);
    k_head<<<192, 64, 0, stream>>>(fo, head_w, head_b, out);
}